// Round 1
// baseline (28595.718 us; speedup 1.0000x reference)
//
#include <hip/hip_runtime.h>

#define T_LEN 512
#define BATCH 64
#define HID   512
#define EMB   512
#define NWG   256

// ---- grid barrier state (lives in d_ws, zeroed by init kernel) ----
struct GBar {
  int leaf[16 * 32];   // leaf g at leaf[g*32], one cacheline apart
  int root; int pad1[31];
  int epoch; int pad2[31];
};

__global__ void init_ws_kernel(int* ws, int n) {
  int stride = gridDim.x * blockDim.x;
  for (int i = blockIdx.x * blockDim.x + threadIdx.x; i < n; i += stride) ws[i] = 0;
}

__device__ __forceinline__ float sigm(float x)      { return 1.f / (1.f + __expf(-x)); }
// saturation-safe tanh: x->+inf => 1, x->-inf => -1, no inf/inf NaN
__device__ __forceinline__ float tanh_fast(float x) { return 1.f - 2.f / (__expf(2.f * x) + 1.f); }

#define FMA4(acc, xv, wv) \
  acc = fmaf((xv).w, (wv).w, fmaf((xv).z, (wv).z, fmaf((xv).y, (wv).y, fmaf((xv).x, (wv).x, (acc)))))

__global__ __launch_bounds__(256) void lstm_pipe(
    const int* __restrict__ src, const int* __restrict__ sen_len,
    const float* __restrict__ emb,
    const float* __restrict__ Wih0, const float* __restrict__ Whh0,
    const float* __restrict__ bih0, const float* __restrict__ bhh0,
    const float* __restrict__ Wih1, const float* __restrict__ Whh1,
    const float* __restrict__ bih1, const float* __restrict__ bhh1,
    float* __restrict__ out,
    int* __restrict__ barp, float* __restrict__ h0ring, float* __restrict__ h1ring)
{
  // LDS: weight slice, k-chunk-major: WlV[kc*16 + (q*4+rj)], kc in [0,256)
  extern __shared__ float4 WlV[];
  GBar* bar = (GBar*)barp;

  const int wg    = blockIdx.x;
  const int layer = wg >> 7;    // 0: layer0 WGs 0..127, 1: layer1 WGs 128..255
  const int w     = wg & 127;   // owns hidden units j in [4w, 4w+4)
  const int tid   = threadIdx.x;
  const int b     = tid >> 2;   // batch element 0..63
  const int rj    = tid & 3;    // which of the 4 owned j's
  const int j     = (w << 2) + rj;

  const float* Wih = layer ? Wih1 : Wih0;
  const float* Whh = layer ? Whh1 : Whh0;

  // Stage 16 rows x 1024 K of weights into LDS (fused [Wih | Whh] along K).
  // idx -> (rowl = idx&15, kc = idx>>4): consecutive lanes write consecutive
  // LDS float4s (conflict-free ds_write_b128).
  for (int idx = tid; idx < 4096; idx += 256) {
    int rowl = idx & 15;          // q*4 + rjj
    int kc   = idx >> 4;          // 0..255
    int q = rowl >> 2, rjj = rowl & 3;
    int grow = q * HID + (w << 2) + rjj;   // global gate row
    int k4 = kc << 2;
    float4 v;
    if (k4 < EMB) v = *(const float4*)(Wih + (size_t)grow * EMB + k4);
    else          v = *(const float4*)(Whh + (size_t)grow * HID + (k4 - EMB));
    WlV[kc * 16 + rowl] = v;
  }

  float bias[4];
#pragma unroll
  for (int q = 0; q < 4; ++q) {
    int r = q * HID + j;
    bias[q] = layer ? (bih1[r] + bhh1[r]) : (bih0[r] + bhh0[r]);
  }
  const int slen = sen_len[b];
  __syncthreads();

  float c = 0.f;   // cell state lives in a register for all 512 steps

  for (int s = 0; s <= T_LEN; ++s) {
    const bool active = (layer == 0) ? (s < T_LEN) : (s >= 1);
    if (active) {
      const int t = (layer == 0) ? s : (s - 1);
      const float* xlow;   // K = 0..511   (input to this layer at step t)
      const float* xhigh;  // K = 512..1023 (own h_{t-1})
      float* hw;           // where to write h_t
      if (layer == 0) {
        xlow  = emb + (size_t)src[t * BATCH + b] * EMB;
        xhigh = h0ring + ((s + 1) & 1) * (BATCH * HID) + b * HID;
        hw    = h0ring + (s & 1) * (BATCH * HID);
      } else {
        xlow  = h0ring + ((s - 1) & 1) * (BATCH * HID) + b * HID;  // h0_t
        xhigh = h1ring + ((s - 1) & 1) * (BATCH * HID) + b * HID;  // h1_{t-1}
        hw    = h1ring + (s & 1) * (BATCH * HID);
      }
      float a0 = bias[0], a1 = bias[1], a2 = bias[2], a3 = bias[3];
#pragma unroll 4
      for (int k = 0; k < EMB; k += 4) {
        float4 xv = *(const float4*)(xlow + k);
        int kc = k >> 2;
        float4 w0 = WlV[kc * 16 + 0  + rj];
        float4 w1 = WlV[kc * 16 + 4  + rj];
        float4 w2 = WlV[kc * 16 + 8  + rj];
        float4 w3 = WlV[kc * 16 + 12 + rj];
        FMA4(a0, xv, w0); FMA4(a1, xv, w1); FMA4(a2, xv, w2); FMA4(a3, xv, w3);
      }
#pragma unroll 4
      for (int k = 0; k < HID; k += 4) {
        float4 xv = *(const float4*)(xhigh + k);
        int kc = (k + EMB) >> 2;
        float4 w0 = WlV[kc * 16 + 0  + rj];
        float4 w1 = WlV[kc * 16 + 4  + rj];
        float4 w2 = WlV[kc * 16 + 8  + rj];
        float4 w3 = WlV[kc * 16 + 12 + rj];
        FMA4(a0, xv, w0); FMA4(a1, xv, w1); FMA4(a2, xv, w2); FMA4(a3, xv, w3);
      }
      float ig = sigm(a0), fg = sigm(a1), gg = tanh_fast(a2), og = sigm(a3);
      c = fmaf(fg, c, ig * gg);
      float h = og * tanh_fast(c);
      hw[b * HID + j] = h;
      if (layer == 1 && t == slen - 1) out[b * HID + j] = h;
    }

    // ---- grid barrier (tree: 16 leaves x 16 WGs), target epoch = s+1 ----
    __syncthreads();
    if (tid == 0) {
      __threadfence();  // release h writes to device scope
      const int target = s + 1;
      const int g = wg >> 4;
      int prev = __hip_atomic_fetch_add(&bar->leaf[g * 32], 1,
                                        __ATOMIC_ACQ_REL, __HIP_MEMORY_SCOPE_AGENT);
      if (prev == 15) {
        __hip_atomic_store(&bar->leaf[g * 32], 0, __ATOMIC_RELAXED, __HIP_MEMORY_SCOPE_AGENT);
        int r = __hip_atomic_fetch_add(&bar->root, 1,
                                       __ATOMIC_ACQ_REL, __HIP_MEMORY_SCOPE_AGENT);
        if (r == 15) {
          __hip_atomic_store(&bar->root, 0, __ATOMIC_RELAXED, __HIP_MEMORY_SCOPE_AGENT);
          __hip_atomic_store(&bar->epoch, target, __ATOMIC_RELEASE, __HIP_MEMORY_SCOPE_AGENT);
        } else {
          while (__hip_atomic_load(&bar->epoch, __ATOMIC_RELAXED, __HIP_MEMORY_SCOPE_AGENT) < target)
            __builtin_amdgcn_s_sleep(2);
        }
      } else {
        while (__hip_atomic_load(&bar->epoch, __ATOMIC_RELAXED, __HIP_MEMORY_SCOPE_AGENT) < target)
          __builtin_amdgcn_s_sleep(2);
      }
    }
    __syncthreads();
    __threadfence();  // acquire: invalidate caches before reading peers' h
  }
}

extern "C" void kernel_launch(void* const* d_in, const int* in_sizes, int n_in,
                              void* d_out, int out_size, void* d_ws, size_t ws_size,
                              hipStream_t stream) {
  const int*   src  = (const int*)d_in[0];
  const int*   slen = (const int*)d_in[1];
  const float* emb  = (const float*)d_in[2];
  const float* Wih0 = (const float*)d_in[3];
  const float* Whh0 = (const float*)d_in[4];
  const float* bih0 = (const float*)d_in[5];
  const float* bhh0 = (const float*)d_in[6];
  const float* Wih1 = (const float*)d_in[7];
  const float* Whh1 = (const float*)d_in[8];
  const float* bih1 = (const float*)d_in[9];
  const float* bhh1 = (const float*)d_in[10];
  float* out = (float*)d_out;

  int*   bar    = (int*)d_ws;
  float* h0ring = (float*)((char*)d_ws + 4096);
  float* h1ring = h0ring + 2 * BATCH * HID;

  // zero barrier state + both h rings (ws is poisoned 0xAA before every launch)
  int zero_ints = (4096 + 2 * (2 * BATCH * HID) * 4) / 4;
  hipLaunchKernelGGL(init_ws_kernel, dim3(64), dim3(256), 0, stream, (int*)d_ws, zero_ints);

  // allow 64 KB dynamic LDS (no-op if already permitted)
  (void)hipFuncSetAttribute((const void*)lstm_pipe,
                            hipFuncAttributeMaxDynamicSharedMemorySize, 65536);

  hipLaunchKernelGGL(lstm_pipe, dim3(NWG), dim3(256), 65536, stream,
                     src, slen, emb, Wih0, Whh0, bih0, bhh0, Wih1, Whh1, bih1, bhh1,
                     out, bar, h0ring, h1ring);
}

// Round 2
// 26909.595 us; speedup vs baseline: 1.0627x; 1.0627x over previous
//
#include <hip/hip_runtime.h>

#define T_LEN 512
#define BATCH 64
#define HID   512
#define EMB   512
#define NWG   256
#define TPB   512
#define RING_SLOT (HID * BATCH)   // 32768 floats per slot, layout [j][b]

// ---- grid barrier state (lives in d_ws, zeroed by init kernel) ----
struct GBar {
  int leaf[16 * 32];   // leaf g at leaf[g*32], one cacheline apart
  int root; int pad1[31];
  int epoch; int pad2[31];
};

__global__ void init_ws_kernel(int* ws, int n) {
  int stride = gridDim.x * blockDim.x;
  for (int i = blockIdx.x * blockDim.x + threadIdx.x; i < n; i += stride) ws[i] = 0;
}

__device__ __forceinline__ float sigm(float x)      { return 1.f / (1.f + __expf(-x)); }
// saturation-safe tanh: x->+inf => 1, x->-inf => -1, no inf/inf NaN
__device__ __forceinline__ float tanh_fast(float x) { return 1.f - 2.f / (__expf(2.f * x) + 1.f); }

// acc (scalar) += dot(xv, wv)
#define DOT_ACC(a, xv, wv) \
  a = fmaf((xv).w, (wv).w, fmaf((xv).z, (wv).z, fmaf((xv).y, (wv).y, fmaf((xv).x, (wv).x, (a)))))
// acc (float4 over b) += s * v (float4 over b)
#define AXPY4(acc, s, v) do { \
  (acc).x = fmaf((s), (v).x, (acc).x); \
  (acc).y = fmaf((s), (v).y, (acc).y); \
  (acc).z = fmaf((s), (v).z, (acc).z); \
  (acc).w = fmaf((s), (v).w, (acc).w); } while (0)

__global__ __launch_bounds__(TPB) void lstm_pipe(
    const int* __restrict__ src, const int* __restrict__ sen_len,
    const float* __restrict__ emb,
    const float* __restrict__ Wih0, const float* __restrict__ Whh0,
    const float* __restrict__ bih0, const float* __restrict__ bhh0,
    const float* __restrict__ Wih1, const float* __restrict__ Whh1,
    const float* __restrict__ bih1, const float* __restrict__ bhh1,
    float* __restrict__ out,
    int* __restrict__ barp, float* __restrict__ h0ring, float* __restrict__ h1ring)
{
  extern __shared__ char smem_raw[];
  float4* WlV  = (float4*)smem_raw;            // 4096 float4 = 64 KB: [kc][16 rows]
  float*  part = (float*)(smem_raw + 65536);   // 8192 floats = 32 KB: [kh][row][b]
  GBar* bar = (GBar*)barp;

  const int wg    = blockIdx.x;
  const int layer = wg >> 7;    // 0: WGs 0..127 (layer0 @ t=s), 1: WGs 128..255 (layer1 @ t=s-1)
  const int w     = wg & 127;   // owns hidden units j in [4w, 4w+4)
  const int tid   = threadIdx.x;
  const int kh    = tid >> 6;   // 0..7  K-segment of 128
  const int lane  = tid & 63;
  const int bg    = lane >> 2;  // 0..15 batch-group (4 batches)
  const int rg    = lane & 3;   // 0..3  j within WG
  const int b0    = bg << 2;    // batches b0..b0+3 (contiguous)
  const int k0    = kh << 7;    // K range [k0, k0+128)

  const float* Wih = layer ? Wih1 : Wih0;
  const float* Whh = layer ? Whh1 : Whh0;

  // Stage 16 rows x 1024 K of fused [Wih | Whh] weights into LDS, [kc][16] float4.
  for (int idx = tid; idx < 4096; idx += TPB) {
    int rowl = idx & 15;          // q*4 + rjj
    int kc   = idx >> 4;          // 0..255
    int q = rowl >> 2, rjj = rowl & 3;
    int grow = q * HID + (w << 2) + rjj;   // global gate row
    int k4 = kc << 2;
    float4 v;
    if (k4 < EMB) v = *(const float4*)(Wih + (size_t)grow * EMB + k4);
    else          v = *(const float4*)(Whh + (size_t)grow * HID + (k4 - EMB));
    WlV[kc * 16 + rowl] = v;
  }

  // Activation-phase identity: threads 0..255 own cell (jj, b); c lives here.
  const int p_b  = tid & 63;
  const int p_jj = (tid >> 6) & 3;
  const int p_jg = (w << 2) + p_jj;
  float bias4[4] = {0.f, 0.f, 0.f, 0.f};
  float c = 0.f;
  int   slen = -2;
  if (tid < 256) {
#pragma unroll
    for (int q = 0; q < 4; ++q) {
      int r = q * HID + p_jg;
      bias4[q] = layer ? (bih1[r] + bhh1[r]) : (bih0[r] + bhh0[r]);
    }
    slen = sen_len[p_b];
  }
  __syncthreads();

  for (int s = 0; s <= T_LEN; ++s) {
    const bool active = (layer == 0) ? (s < T_LEN) : (s >= 1);
    if (active) {
      const int t = (layer == 0) ? s : (s - 1);
      float4 acc[4];
#pragma unroll
      for (int q = 0; q < 4; ++q) acc[q] = make_float4(0.f, 0.f, 0.f, 0.f);

      if (layer == 0 && kh < 4) {
        // ---- embedding-gather mode: x[b][k] rows of emb, K = k0..k0+128 ----
        const int* st = src + t * BATCH + b0;
        const float* e0 = emb + (size_t)st[0] * EMB;
        const float* e1 = emb + (size_t)st[1] * EMB;
        const float* e2 = emb + (size_t)st[2] * EMB;
        const float* e3 = emb + (size_t)st[3] * EMB;
#pragma unroll 4
        for (int kk = 0; kk < 128; kk += 4) {
          const int k  = k0 + kk;
          const int kc = k >> 2;
          float4 x0 = *(const float4*)(e0 + k);
          float4 x1 = *(const float4*)(e1 + k);
          float4 x2 = *(const float4*)(e2 + k);
          float4 x3 = *(const float4*)(e3 + k);
#pragma unroll
          for (int q = 0; q < 4; ++q) {
            float4 wq = WlV[kc * 16 + (q << 2) + rg];
            DOT_ACC(acc[q].x, x0, wq);
            DOT_ACC(acc[q].y, x1, wq);
            DOT_ACC(acc[q].z, x2, wq);
            DOT_ACC(acc[q].w, x3, wq);
          }
        }
      } else {
        // ---- transposed-ring mode: x^T[k][b], contiguous over b ----
        const float* xT;
        if (layer == 0) {
          // own h_{t-1}: K 512..1023 -> j = k0-512 ..
          xT = h0ring + ((s + 1) & 1) * RING_SLOT + (k0 - EMB) * BATCH;
        } else if (kh < 4) {
          // h0_t from layer 0 (produced at slot s-1): K 0..511
          xT = h0ring + ((s - 1) & 1) * RING_SLOT + k0 * BATCH;
        } else {
          // own h1_{t-1}: K 512..1023
          xT = h1ring + ((s - 1) & 1) * RING_SLOT + (k0 - EMB) * BATCH;
        }
        const float* p = xT + b0;
#pragma unroll 4
        for (int kk = 0; kk < 128; kk += 4) {
          const int kc = (k0 + kk) >> 2;
          float4 r0 = *(const float4*)(p + (kk + 0) * BATCH);
          float4 r1 = *(const float4*)(p + (kk + 1) * BATCH);
          float4 r2 = *(const float4*)(p + (kk + 2) * BATCH);
          float4 r3 = *(const float4*)(p + (kk + 3) * BATCH);
#pragma unroll
          for (int q = 0; q < 4; ++q) {
            float4 wq = WlV[kc * 16 + (q << 2) + rg];
            AXPY4(acc[q], wq.x, r0);
            AXPY4(acc[q], wq.y, r1);
            AXPY4(acc[q], wq.z, r2);
            AXPY4(acc[q], wq.w, r3);
          }
        }
      }
      // write partials: part[kh][row][b], row = q*4+rg, b = b0..b0+3
#pragma unroll
      for (int q = 0; q < 4; ++q)
        *(float4*)(part + (kh << 10) + (((q << 2) + rg) << 6) + b0) = acc[q];
    }

    __syncthreads();  // partials visible

    if (active && tid < 256) {
      float g4[4];
#pragma unroll
      for (int q = 0; q < 4; ++q) {
        float a = bias4[q];
        const int base = (((q << 2) + p_jj) << 6) + p_b;
#pragma unroll
        for (int kk = 0; kk < 8; ++kk) a += part[(kk << 10) + base];
        g4[q] = a;
      }
      float ig = sigm(g4[0]), fg = sigm(g4[1]), gg = tanh_fast(g4[2]), og = sigm(g4[3]);
      c = fmaf(fg, c, ig * gg);
      float h = og * tanh_fast(c);
      float* ring = (layer == 0 ? h0ring : h1ring) + (s & 1) * RING_SLOT;
      ring[p_jg * BATCH + p_b] = h;   // transposed store [j][b], coalesced per wave
      if (layer == 1) {
        const int t = s - 1;
        if (t == slen - 1) out[p_b * HID + p_jg] = h;
      }
    }

    // ---- grid barrier (tree: 16 leaves x 16 WGs), target epoch = s+1 ----
    __syncthreads();
    if (tid == 0) {
      __threadfence();  // release h writes to device scope
      const int target = s + 1;
      const int g = wg >> 4;
      int prev = __hip_atomic_fetch_add(&bar->leaf[g * 32], 1,
                                        __ATOMIC_ACQ_REL, __HIP_MEMORY_SCOPE_AGENT);
      if (prev == 15) {
        __hip_atomic_store(&bar->leaf[g * 32], 0, __ATOMIC_RELAXED, __HIP_MEMORY_SCOPE_AGENT);
        int r = __hip_atomic_fetch_add(&bar->root, 1,
                                       __ATOMIC_ACQ_REL, __HIP_MEMORY_SCOPE_AGENT);
        if (r == 15) {
          __hip_atomic_store(&bar->root, 0, __ATOMIC_RELAXED, __HIP_MEMORY_SCOPE_AGENT);
          __hip_atomic_store(&bar->epoch, target, __ATOMIC_RELEASE, __HIP_MEMORY_SCOPE_AGENT);
        } else {
          while (__hip_atomic_load(&bar->epoch, __ATOMIC_RELAXED, __HIP_MEMORY_SCOPE_AGENT) < target)
            __builtin_amdgcn_s_sleep(2);
        }
      } else {
        while (__hip_atomic_load(&bar->epoch, __ATOMIC_RELAXED, __HIP_MEMORY_SCOPE_AGENT) < target)
          __builtin_amdgcn_s_sleep(2);
      }
    }
    __syncthreads();
    __threadfence();  // acquire: see peers' h before reading rings
  }
}

extern "C" void kernel_launch(void* const* d_in, const int* in_sizes, int n_in,
                              void* d_out, int out_size, void* d_ws, size_t ws_size,
                              hipStream_t stream) {
  const int*   src  = (const int*)d_in[0];
  const int*   slen = (const int*)d_in[1];
  const float* emb  = (const float*)d_in[2];
  const float* Wih0 = (const float*)d_in[3];
  const float* Whh0 = (const float*)d_in[4];
  const float* bih0 = (const float*)d_in[5];
  const float* bhh0 = (const float*)d_in[6];
  const float* Wih1 = (const float*)d_in[7];
  const float* Whh1 = (const float*)d_in[8];
  const float* bih1 = (const float*)d_in[9];
  const float* bhh1 = (const float*)d_in[10];
  float* out = (float*)d_out;

  int*   bar    = (int*)d_ws;
  float* h0ring = (float*)((char*)d_ws + 4096);
  float* h1ring = h0ring + 2 * RING_SLOT;

  // zero barrier state + all 4 ring slots (ws is poisoned 0xAA before every launch)
  int zero_ints = (4096 + 4 * RING_SLOT * 4) / 4;
  hipLaunchKernelGGL(init_ws_kernel, dim3(64), dim3(256), 0, stream, (int*)d_ws, zero_ints);

  (void)hipFuncSetAttribute((const void*)lstm_pipe,
                            hipFuncAttributeMaxDynamicSharedMemorySize, 98304);

  hipLaunchKernelGGL(lstm_pipe, dim3(NWG), dim3(TPB), 98304, stream,
                     src, slen, emb, Wih0, Whh0, bih0, bhh0, Wih1, Whh1, bih1, bhh1,
                     out, bar, h0ring, h1ring);
}

// Round 3
// 11451.856 us; speedup vs baseline: 2.4970x; 2.3498x over previous
//
#include <hip/hip_runtime.h>

#define T_LEN 512
#define BATCH 64
#define HID   512
#define EMB   512
#define NWG   256
#define TPB   512
#define RING_SLOT (HID * BATCH)   // 32768 floats per slot, layout [j][b]

// ---- grid barrier state (lives in d_ws, zeroed by init kernel) ----
// Hierarchical: arrival = leaf[16] -> root; release = epoch -> gep[16].
struct GBar {
  int leaf[16 * 32];   // arrival counter per group, one cacheline apart
  int root; int pad1[31];
  int epoch; int pad2[31];
  int gep[16 * 32];    // per-group release epoch, one cacheline apart
};

__global__ void init_ws_kernel(int* ws, int n) {
  int stride = gridDim.x * blockDim.x;
  for (int i = blockIdx.x * blockDim.x + threadIdx.x; i < n; i += stride) ws[i] = 0;
}

__device__ __forceinline__ float sigm(float x)      { return 1.f / (1.f + __expf(-x)); }
// saturation-safe tanh: x->+inf => 1, x->-inf => -1, no inf/inf NaN
__device__ __forceinline__ float tanh_fast(float x) { return 1.f - 2.f / (__expf(2.f * x) + 1.f); }

// acc (scalar) += dot(xv, wv)
#define DOT_ACC(a, xv, wv) \
  a = fmaf((xv).w, (wv).w, fmaf((xv).z, (wv).z, fmaf((xv).y, (wv).y, fmaf((xv).x, (wv).x, (a)))))
// acc (float4 over b) += s * v (float4 over b)
#define AXPY4(acc, s, v) do { \
  (acc).x = fmaf((s), (v).x, (acc).x); \
  (acc).y = fmaf((s), (v).y, (acc).y); \
  (acc).z = fmaf((s), (v).z, (acc).z); \
  (acc).w = fmaf((s), (v).w, (acc).w); } while (0)

__global__ __launch_bounds__(TPB) void lstm_pipe(
    const int* __restrict__ src, const int* __restrict__ sen_len,
    const float* __restrict__ emb,
    const float* __restrict__ Wih0, const float* __restrict__ Whh0,
    const float* __restrict__ bih0, const float* __restrict__ bhh0,
    const float* __restrict__ Wih1, const float* __restrict__ Whh1,
    const float* __restrict__ bih1, const float* __restrict__ bhh1,
    float* __restrict__ out,
    int* __restrict__ barp, float* __restrict__ h0ring, float* __restrict__ h1ring)
{
  extern __shared__ char smem_raw[];
  float4* WlV  = (float4*)smem_raw;            // 4096 float4 = 64 KB: [kc][16 rows]
  float*  part = (float*)(smem_raw + 65536);   // 8192 floats = 32 KB: [kh][row][b]
  GBar* bar = (GBar*)barp;

  const int wg    = blockIdx.x;
  const int layer = wg >> 7;    // 0: WGs 0..127 (layer0 @ t=s), 1: WGs 128..255 (layer1 @ t=s-1)
  const int w     = wg & 127;   // owns hidden units j in [4w, 4w+4)
  const int tid   = threadIdx.x;
  const int kh    = tid >> 6;   // 0..7  K-segment of 128
  const int lane  = tid & 63;
  const int bg    = lane >> 2;  // 0..15 batch-group (4 batches)
  const int rg    = lane & 3;   // 0..3  j within WG
  const int b0    = bg << 2;    // batches b0..b0+3 (contiguous)
  const int k0    = kh << 7;    // K range [k0, k0+128)

  const float* Wih = layer ? Wih1 : Wih0;
  const float* Whh = layer ? Whh1 : Whh0;

  // Stage 16 rows x 1024 K of fused [Wih | Whh] weights into LDS, [kc][16] float4.
  for (int idx = tid; idx < 4096; idx += TPB) {
    int rowl = idx & 15;          // q*4 + rjj
    int kc   = idx >> 4;          // 0..255
    int q = rowl >> 2, rjj = rowl & 3;
    int grow = q * HID + (w << 2) + rjj;   // global gate row
    int k4 = kc << 2;
    float4 v;
    if (k4 < EMB) v = *(const float4*)(Wih + (size_t)grow * EMB + k4);
    else          v = *(const float4*)(Whh + (size_t)grow * HID + (k4 - EMB));
    WlV[kc * 16 + rowl] = v;
  }

  // Activation-phase identity: threads 0..255 own cell (jj, b); c lives here.
  const int p_b  = tid & 63;
  const int p_jj = (tid >> 6) & 3;
  const int p_jg = (w << 2) + p_jj;
  float bias4[4] = {0.f, 0.f, 0.f, 0.f};
  float c = 0.f;
  int   slen = -2;
  if (tid < 256) {
#pragma unroll
    for (int q = 0; q < 4; ++q) {
      int r = q * HID + p_jg;
      bias4[q] = layer ? (bih1[r] + bhh1[r]) : (bih0[r] + bhh0[r]);
    }
    slen = sen_len[p_b];
  }
  __syncthreads();

  for (int s = 0; s <= T_LEN; ++s) {
    const bool active = (layer == 0) ? (s < T_LEN) : (s >= 1);
    if (active) {
      const int t = (layer == 0) ? s : (s - 1);
      float4 acc[4];
#pragma unroll
      for (int q = 0; q < 4; ++q) acc[q] = make_float4(0.f, 0.f, 0.f, 0.f);

      if (layer == 0 && kh < 4) {
        // ---- embedding-gather mode: x[b][k] rows of emb, K = k0..k0+128 ----
        const int* st = src + t * BATCH + b0;
        const float* e0 = emb + (size_t)st[0] * EMB;
        const float* e1 = emb + (size_t)st[1] * EMB;
        const float* e2 = emb + (size_t)st[2] * EMB;
        const float* e3 = emb + (size_t)st[3] * EMB;
#pragma unroll 4
        for (int kk = 0; kk < 128; kk += 4) {
          const int k  = k0 + kk;
          const int kc = k >> 2;
          float4 x0 = *(const float4*)(e0 + k);
          float4 x1 = *(const float4*)(e1 + k);
          float4 x2 = *(const float4*)(e2 + k);
          float4 x3 = *(const float4*)(e3 + k);
#pragma unroll
          for (int q = 0; q < 4; ++q) {
            float4 wq = WlV[kc * 16 + (q << 2) + rg];
            DOT_ACC(acc[q].x, x0, wq);
            DOT_ACC(acc[q].y, x1, wq);
            DOT_ACC(acc[q].z, x2, wq);
            DOT_ACC(acc[q].w, x3, wq);
          }
        }
      } else {
        // ---- transposed-ring mode: x^T[k][b], contiguous over b ----
        const float* xT;
        if (layer == 0) {
          xT = h0ring + ((s + 1) & 1) * RING_SLOT + (k0 - EMB) * BATCH;
        } else if (kh < 4) {
          xT = h0ring + ((s - 1) & 1) * RING_SLOT + k0 * BATCH;
        } else {
          xT = h1ring + ((s - 1) & 1) * RING_SLOT + (k0 - EMB) * BATCH;
        }
        const float* p = xT + b0;
#pragma unroll 4
        for (int kk = 0; kk < 128; kk += 4) {
          const int kc = (k0 + kk) >> 2;
          float4 r0 = *(const float4*)(p + (kk + 0) * BATCH);
          float4 r1 = *(const float4*)(p + (kk + 1) * BATCH);
          float4 r2 = *(const float4*)(p + (kk + 2) * BATCH);
          float4 r3 = *(const float4*)(p + (kk + 3) * BATCH);
#pragma unroll
          for (int q = 0; q < 4; ++q) {
            float4 wq = WlV[kc * 16 + (q << 2) + rg];
            AXPY4(acc[q], wq.x, r0);
            AXPY4(acc[q], wq.y, r1);
            AXPY4(acc[q], wq.z, r2);
            AXPY4(acc[q], wq.w, r3);
          }
        }
      }
      // write partials: part[kh][row][b], row = q*4+rg, b = b0..b0+3
#pragma unroll
      for (int q = 0; q < 4; ++q)
        *(float4*)(part + (kh << 10) + (((q << 2) + rg) << 6) + b0) = acc[q];
    }

    __syncthreads();  // partials visible

    if (active && tid < 256) {
      float g4[4];
#pragma unroll
      for (int q = 0; q < 4; ++q) {
        float a = bias4[q];
        const int base = (((q << 2) + p_jj) << 6) + p_b;
#pragma unroll
        for (int kk = 0; kk < 8; ++kk) a += part[(kk << 10) + base];
        g4[q] = a;
      }
      float ig = sigm(g4[0]), fg = sigm(g4[1]), gg = tanh_fast(g4[2]), og = sigm(g4[3]);
      c = fmaf(fg, c, ig * gg);
      float h = og * tanh_fast(c);
      float* ring = (layer == 0 ? h0ring : h1ring) + (s & 1) * RING_SLOT;
      ring[p_jg * BATCH + p_b] = h;   // transposed store [j][b], coalesced per wave
      if (layer == 1) {
        const int t = s - 1;
        if (t == slen - 1) out[p_b * HID + p_jg] = h;
      }
    }

    // ---- hierarchical grid barrier, target epoch = s+1 ----
    // Arrival: leaf(16x16) -> root. Release: epoch -> per-group gep lines.
    // Max pollers on any one line: 16 (was 255) — kills same-line contention.
    // Spins are RELAXED; one ACQUIRE on exit gives the (single) buffer_inv.
    // __syncthreads() before this drains all waves' ring stores (vmcnt(0)),
    // so tid0's RELEASE fetch_add covers the whole WG's writes.
    __syncthreads();
    if (tid == 0) {
      const int target = s + 1;
      int* leafp = &bar->leaf[(wg >> 4) * 32];
      int* gepp  = &bar->gep[(wg >> 4) * 32];
      int prev = __hip_atomic_fetch_add(leafp, 1, __ATOMIC_ACQ_REL, __HIP_MEMORY_SCOPE_AGENT);
      if (prev == 15) {
        __hip_atomic_store(leafp, 0, __ATOMIC_RELAXED, __HIP_MEMORY_SCOPE_AGENT);
        int r = __hip_atomic_fetch_add(&bar->root, 1, __ATOMIC_ACQ_REL, __HIP_MEMORY_SCOPE_AGENT);
        if (r == 15) {
          __hip_atomic_store(&bar->root, 0, __ATOMIC_RELAXED, __HIP_MEMORY_SCOPE_AGENT);
          __hip_atomic_store(&bar->epoch, target, __ATOMIC_RELEASE, __HIP_MEMORY_SCOPE_AGENT);
        } else {
          while (__hip_atomic_load(&bar->epoch, __ATOMIC_RELAXED, __HIP_MEMORY_SCOPE_AGENT) < target)
            __builtin_amdgcn_s_sleep(1);
          (void)__hip_atomic_load(&bar->epoch, __ATOMIC_ACQUIRE, __HIP_MEMORY_SCOPE_AGENT);
        }
        __hip_atomic_store(gepp, target, __ATOMIC_RELEASE, __HIP_MEMORY_SCOPE_AGENT);
      } else {
        while (__hip_atomic_load(gepp, __ATOMIC_RELAXED, __HIP_MEMORY_SCOPE_AGENT) < target)
          __builtin_amdgcn_s_sleep(1);
        (void)__hip_atomic_load(gepp, __ATOMIC_ACQUIRE, __HIP_MEMORY_SCOPE_AGENT);
      }
    }
    __syncthreads();
  }
}

extern "C" void kernel_launch(void* const* d_in, const int* in_sizes, int n_in,
                              void* d_out, int out_size, void* d_ws, size_t ws_size,
                              hipStream_t stream) {
  const int*   src  = (const int*)d_in[0];
  const int*   slen = (const int*)d_in[1];
  const float* emb  = (const float*)d_in[2];
  const float* Wih0 = (const float*)d_in[3];
  const float* Whh0 = (const float*)d_in[4];
  const float* bih0 = (const float*)d_in[5];
  const float* bhh0 = (const float*)d_in[6];
  const float* Wih1 = (const float*)d_in[7];
  const float* Whh1 = (const float*)d_in[8];
  const float* bih1 = (const float*)d_in[9];
  const float* bhh1 = (const float*)d_in[10];
  float* out = (float*)d_out;

  int*   bar    = (int*)d_ws;
  float* h0ring = (float*)((char*)d_ws + 8192);
  float* h1ring = h0ring + 2 * RING_SLOT;

  // zero barrier state + all 4 ring slots (ws is poisoned 0xAA before every launch)
  int zero_ints = (8192 + 4 * RING_SLOT * 4) / 4;
  hipLaunchKernelGGL(init_ws_kernel, dim3(64), dim3(256), 0, stream, (int*)d_ws, zero_ints);

  (void)hipFuncSetAttribute((const void*)lstm_pipe,
                            hipFuncAttributeMaxDynamicSharedMemorySize, 98304);

  hipLaunchKernelGGL(lstm_pipe, dim3(NWG), dim3(TPB), 98304, stream,
                     src, slen, emb, Wih0, Whh0, bih0, bhh0, Wih1, Whh1, bih1, bhh1,
                     out, bar, h0ring, h1ring);
}

// Round 5
// 7830.696 us; speedup vs baseline: 3.6517x; 1.4624x over previous
//
#include <hip/hip_runtime.h>

#define T_LEN 512
#define BATCH 64
#define HID   512
#define EMB   512
#define NWG   256
#define TPB   512
#define RING_SLOT (HID * BATCH)   // 32768 floats per slot, layout [j][b]

// ---- grid barrier state (lives in d_ws, zeroed by init kernel) ----
// Monotonic counters (never reset): leaf[g] gets 16 incs/slot, root gets 16.
// Release fans out: epoch (root winner) -> gep[g] (group winners).
struct GBar {
  int leaf[16 * 32];   // arrival counter per group, one cacheline apart
  int root; int pad1[31];
  int epoch; int pad2[31];
  int gep[16 * 32];    // per-group release epoch, one cacheline apart
};

__global__ void init_ws_kernel(int* ws, int n) {
  int stride = gridDim.x * blockDim.x;
  for (int i = blockIdx.x * blockDim.x + threadIdx.x; i < n; i += stride) ws[i] = 0;
}

__device__ __forceinline__ float sigm(float x)      { return 1.f / (1.f + __expf(-x)); }
// saturation-safe tanh: x->+inf => 1, x->-inf => -1, no inf/inf NaN
__device__ __forceinline__ float tanh_fast(float x) { return 1.f - 2.f / (__expf(2.f * x) + 1.f); }

// coherent (device-scope, cache-bypassing) scalar access — no fences needed
__device__ __forceinline__ float cload(const float* p) {
  return __hip_atomic_load((const float*)p, __ATOMIC_RELAXED, __HIP_MEMORY_SCOPE_AGENT);
}
__device__ __forceinline__ void cstore(float* p, float v) {
  __hip_atomic_store(p, v, __ATOMIC_RELAXED, __HIP_MEMORY_SCOPE_AGENT);
}

// acc (scalar) += dot(xv, wv)
#define DOT_ACC(a, xv, wv) \
  a = fmaf((xv).w, (wv).w, fmaf((xv).z, (wv).z, fmaf((xv).y, (wv).y, fmaf((xv).x, (wv).x, (a)))))
// acc (float4 over b) += s * v (float4 over b)
#define AXPY4(acc, s, v) do { \
  (acc).x = fmaf((s), (v).x, (acc).x); \
  (acc).y = fmaf((s), (v).y, (acc).y); \
  (acc).z = fmaf((s), (v).z, (acc).z); \
  (acc).w = fmaf((s), (v).w, (acc).w); } while (0)

__global__ __launch_bounds__(TPB) void lstm_pipe(
    const int* __restrict__ src, const int* __restrict__ sen_len,
    const float* __restrict__ emb,
    const float* __restrict__ Wih0, const float* __restrict__ Whh0,
    const float* __restrict__ bih0, const float* __restrict__ bhh0,
    const float* __restrict__ Wih1, const float* __restrict__ Whh1,
    const float* __restrict__ bih1, const float* __restrict__ bhh1,
    float* __restrict__ out,
    int* __restrict__ barp, float* __restrict__ h0ring, float* __restrict__ h1ring)
{
  extern __shared__ char smem_raw[];
  float4* WlV  = (float4*)smem_raw;            // 4096 float4 = 64 KB: [kc][16 rows]
  float*  part = (float*)(smem_raw + 65536);   // 8192 floats = 32 KB: [kh][row][b]
  GBar* bar = (GBar*)barp;

  const int wg    = blockIdx.x;
  const int layer = wg >> 7;    // 0: WGs 0..127 (layer0 @ t=s), 1: WGs 128..255 (layer1 @ t=s-1)
  const int w     = wg & 127;   // owns hidden units j in [4w, 4w+4)
  const int tid   = threadIdx.x;
  const int kh    = tid >> 6;   // 0..7  K-segment of 128
  const int lane  = tid & 63;
  const int bg    = lane >> 2;  // 0..15 batch-group (4 batches)
  const int rg    = lane & 3;   // 0..3  j within WG
  const int b0    = bg << 2;    // batches b0..b0+3 (contiguous)
  const int k0    = kh << 7;    // K range [k0, k0+128)

  const float* Wih = layer ? Wih1 : Wih0;
  const float* Whh = layer ? Whh1 : Whh0;

  // Stage 16 rows x 1024 K of fused [Wih | Whh] weights into LDS, [kc][16] float4.
  for (int idx = tid; idx < 4096; idx += TPB) {
    int rowl = idx & 15;          // q*4 + rjj
    int kc   = idx >> 4;          // 0..255
    int q = rowl >> 2, rjj = rowl & 3;
    int grow = q * HID + (w << 2) + rjj;   // global gate row
    int k4 = kc << 2;
    float4 v;
    if (k4 < EMB) v = *(const float4*)(Wih + (size_t)grow * EMB + k4);
    else          v = *(const float4*)(Whh + (size_t)grow * HID + (k4 - EMB));
    WlV[kc * 16 + rowl] = v;
  }

  // Activation-phase identity: threads 0..255 own cell (jj, b); c lives here.
  const int p_b  = tid & 63;
  const int p_jj = (tid >> 6) & 3;
  const int p_jg = (w << 2) + p_jj;
  float bias4[4] = {0.f, 0.f, 0.f, 0.f};
  float c = 0.f;
  int   slen = -2;
  if (tid < 256) {
#pragma unroll
    for (int q = 0; q < 4; ++q) {
      int r = q * HID + p_jg;
      bias4[q] = layer ? (bih1[r] + bhh1[r]) : (bih0[r] + bhh0[r]);
    }
    slen = sen_len[p_b];
  }
  __syncthreads();

  for (int s = 0; s <= T_LEN; ++s) {
    const bool active = (layer == 0) ? (s < T_LEN) : (s >= 1);
    if (active) {
      const int t = (layer == 0) ? s : (s - 1);
      float4 acc[4];
#pragma unroll
      for (int q = 0; q < 4; ++q) acc[q] = make_float4(0.f, 0.f, 0.f, 0.f);

      if (layer == 0 && kh < 4) {
        // ---- embedding-gather mode: read-only data, normal cached loads ----
        const int* st = src + t * BATCH + b0;
        const float* e0 = emb + (size_t)st[0] * EMB;
        const float* e1 = emb + (size_t)st[1] * EMB;
        const float* e2 = emb + (size_t)st[2] * EMB;
        const float* e3 = emb + (size_t)st[3] * EMB;
#pragma unroll 4
        for (int kk = 0; kk < 128; kk += 4) {
          const int k  = k0 + kk;
          const int kc = k >> 2;
          float4 x0 = *(const float4*)(e0 + k);
          float4 x1 = *(const float4*)(e1 + k);
          float4 x2 = *(const float4*)(e2 + k);
          float4 x3 = *(const float4*)(e3 + k);
#pragma unroll
          for (int q = 0; q < 4; ++q) {
            float4 wq = WlV[kc * 16 + (q << 2) + rg];
            DOT_ACC(acc[q].x, x0, wq);
            DOT_ACC(acc[q].y, x1, wq);
            DOT_ACC(acc[q].z, x2, wq);
            DOT_ACC(acc[q].w, x3, wq);
          }
        }
      } else {
        // ---- transposed-ring mode: coherent scalar loads (sc0 sc1, IF-served) ----
        const float* xT;
        if (layer == 0) {
          xT = h0ring + ((s + 1) & 1) * RING_SLOT + (k0 - EMB) * BATCH;
        } else if (kh < 4) {
          xT = h0ring + ((s - 1) & 1) * RING_SLOT + k0 * BATCH;
        } else {
          xT = h1ring + ((s - 1) & 1) * RING_SLOT + (k0 - EMB) * BATCH;
        }
        const float* p = xT + b0;
#pragma unroll 4
        for (int kk = 0; kk < 128; kk += 4) {
          const int kc = (k0 + kk) >> 2;
          float4 r0, r1, r2, r3;
          r0.x = cload(p + (kk + 0) * BATCH + 0); r0.y = cload(p + (kk + 0) * BATCH + 1);
          r0.z = cload(p + (kk + 0) * BATCH + 2); r0.w = cload(p + (kk + 0) * BATCH + 3);
          r1.x = cload(p + (kk + 1) * BATCH + 0); r1.y = cload(p + (kk + 1) * BATCH + 1);
          r1.z = cload(p + (kk + 1) * BATCH + 2); r1.w = cload(p + (kk + 1) * BATCH + 3);
          r2.x = cload(p + (kk + 2) * BATCH + 0); r2.y = cload(p + (kk + 2) * BATCH + 1);
          r2.z = cload(p + (kk + 2) * BATCH + 2); r2.w = cload(p + (kk + 2) * BATCH + 3);
          r3.x = cload(p + (kk + 3) * BATCH + 0); r3.y = cload(p + (kk + 3) * BATCH + 1);
          r3.z = cload(p + (kk + 3) * BATCH + 2); r3.w = cload(p + (kk + 3) * BATCH + 3);
#pragma unroll
          for (int q = 0; q < 4; ++q) {
            float4 wq = WlV[kc * 16 + (q << 2) + rg];
            AXPY4(acc[q], wq.x, r0);
            AXPY4(acc[q], wq.y, r1);
            AXPY4(acc[q], wq.z, r2);
            AXPY4(acc[q], wq.w, r3);
          }
        }
      }
      // write partials: part[kh][row][b], row = q*4+rg, b = b0..b0+3
#pragma unroll
      for (int q = 0; q < 4; ++q)
        *(float4*)(part + (kh << 10) + (((q << 2) + rg) << 6) + b0) = acc[q];
    }

    __syncthreads();  // partials visible

    if (active && tid < 256) {
      float g4[4];
#pragma unroll
      for (int q = 0; q < 4; ++q) {
        float a = bias4[q];
        const int base = (((q << 2) + p_jj) << 6) + p_b;
#pragma unroll
        for (int kk = 0; kk < 8; ++kk) a += part[(kk << 10) + base];
        g4[q] = a;
      }
      float ig = sigm(g4[0]), fg = sigm(g4[1]), gg = tanh_fast(g4[2]), og = sigm(g4[3]);
      c = fmaf(fg, c, ig * gg);
      float h = og * tanh_fast(c);
      float* ring = (layer == 0 ? h0ring : h1ring) + (s & 1) * RING_SLOT;
      cstore(ring + p_jg * BATCH + p_b, h);   // coherent store [j][b], coalesced
      if (layer == 1) {
        const int t = s - 1;
        if (t == slen - 1) out[p_b * HID + p_jg] = h;
      }
    }

    // ---- hierarchical grid barrier, all-RELAXED, monotonic counters ----
    // __syncthreads() drains vmcnt(0): every coherent h-store is committed at
    // the IF coherence point before tid0's arrival increment. Consumers read
    // ring data with coherent loads after observing the release — no cache
    // maintenance (buffer_inv / buffer_wbl2) anywhere.
    __syncthreads();
    if (tid == 0) {
      const int target = s + 1;
      int* leafp = &bar->leaf[(wg >> 4) * 32];
      int* gepp  = &bar->gep[(wg >> 4) * 32];
      int prev = __hip_atomic_fetch_add(leafp, 1, __ATOMIC_RELAXED, __HIP_MEMORY_SCOPE_AGENT);
      if ((prev & 15) == 15) {   // 16th arrival of this slot in this group
        int r = __hip_atomic_fetch_add(&bar->root, 1, __ATOMIC_RELAXED, __HIP_MEMORY_SCOPE_AGENT);
        if ((r & 15) == 15) {    // 16th group — release everyone
          __hip_atomic_store(&bar->epoch, target, __ATOMIC_RELAXED, __HIP_MEMORY_SCOPE_AGENT);
        } else {
          while (__hip_atomic_load(&bar->epoch, __ATOMIC_RELAXED, __HIP_MEMORY_SCOPE_AGENT) < target)
            __builtin_amdgcn_s_sleep(1);
        }
        __hip_atomic_store(gepp, target, __ATOMIC_RELAXED, __HIP_MEMORY_SCOPE_AGENT);
      } else {
        while (__hip_atomic_load(gepp, __ATOMIC_RELAXED, __HIP_MEMORY_SCOPE_AGENT) < target)
          __builtin_amdgcn_s_sleep(1);
      }
    }
    __syncthreads();
  }
}

extern "C" void kernel_launch(void* const* d_in, const int* in_sizes, int n_in,
                              void* d_out, int out_size, void* d_ws, size_t ws_size,
                              hipStream_t stream) {
  const int*   src  = (const int*)d_in[0];
  const int*   slen = (const int*)d_in[1];
  const float* emb  = (const float*)d_in[2];
  const float* Wih0 = (const float*)d_in[3];
  const float* Whh0 = (const float*)d_in[4];
  const float* bih0 = (const float*)d_in[5];
  const float* bhh0 = (const float*)d_in[6];
  const float* Wih1 = (const float*)d_in[7];
  const float* Whh1 = (const float*)d_in[8];
  const float* bih1 = (const float*)d_in[9];
  const float* bhh1 = (const float*)d_in[10];
  float* out = (float*)d_out;

  int*   bar    = (int*)d_ws;
  float* h0ring = (float*)((char*)d_ws + 8192);
  float* h1ring = h0ring + 2 * RING_SLOT;

  // zero barrier state + all 4 ring slots (ws is poisoned 0xAA before every launch)
  int zero_ints = (8192 + 4 * RING_SLOT * 4) / 4;
  hipLaunchKernelGGL(init_ws_kernel, dim3(64), dim3(256), 0, stream, (int*)d_ws, zero_ints);

  (void)hipFuncSetAttribute((const void*)lstm_pipe,
                            hipFuncAttributeMaxDynamicSharedMemorySize, 98304);

  hipLaunchKernelGGL(lstm_pipe, dim3(NWG), dim3(TPB), 98304, stream,
                     src, slen, emb, Wih0, Whh0, bih0, bhh0, Wih1, Whh1, bih1, bhh1,
                     out, bar, h0ring, h1ring);
}

// Round 7
// 6016.071 us; speedup vs baseline: 4.7532x; 1.3016x over previous
//
#include <hip/hip_runtime.h>

#define T_LEN 512
#define BATCH 64
#define HID   512
#define EMB   512
#define NWG   256
#define TPB   512
#define RING_SLOT (HID * BATCH)   // 32768 floats per slot, layout [j][b]

// ---- grid barrier state (lives in d_ws, zeroed by init kernel) ----
// Monotonic counters (never reset): leaf[g] gets 16 incs/slot, root gets 16.
// Release fans out: epoch (root winner) -> gep[g] (group winners).
struct GBar {
  int leaf[16 * 32];   // arrival counter per group, one cacheline apart
  int root; int pad1[31];
  int epoch; int pad2[31];
  int gep[16 * 32];    // per-group release epoch, one cacheline apart
};

__global__ void init_ws_kernel(int* ws, int n) {
  int stride = gridDim.x * blockDim.x;
  for (int i = blockIdx.x * blockDim.x + threadIdx.x; i < n; i += stride) ws[i] = 0;
}

__device__ __forceinline__ float sigm(float x)      { return 1.f / (1.f + __expf(-x)); }
// saturation-safe tanh: x->+inf => 1, x->-inf => -1, no inf/inf NaN
__device__ __forceinline__ float tanh_fast(float x) { return 1.f - 2.f / (__expf(2.f * x) + 1.f); }

// coherent (device-scope, cache-bypassing) scalar store — no fences needed
__device__ __forceinline__ void cstore(float* p, float v) {
  __hip_atomic_store(p, v, __ATOMIC_RELAXED, __HIP_MEMORY_SCOPE_AGENT);
}

// ---- coherent 16B load, fire-and-forget (NO waitcnt): sc0 sc1 bypass L1/L2
// so no stale lines are possible; completion enforced by WAIT_VM below.
template <int I, int N>
struct Issue16 {
  static __device__ __forceinline__ void go(float4* dst, const float* p) {
    asm volatile("global_load_dwordx4 %0, %1, off offset:%2 sc0 sc1"
                 : "=v"(dst[I]) : "v"(p), "i"(I * 256));
    Issue16<I + 1, N>::go(dst, p);
  }
};
template <int N>
struct Issue16<N, N> {
  static __device__ __forceinline__ void go(float4*, const float*) {}
};

// s_waitcnt vmcnt(n) as a hard scheduling fence. asm-volatile statements are
// mutually ordered (so the wait stays after the Issue16 loads); the
// sched_barrier(0) pair pins ALL other instructions (incl. the consuming
// FMAs) on their side of the wait. vmcnt is FIFO: waiting to <=16 after
// issuing the next 16 loads guarantees the previous 16 (and any earlier
// stores) have landed.
#define WAIT_VM(n) do {                                     \
    __builtin_amdgcn_sched_barrier(0);                      \
    asm volatile("s_waitcnt vmcnt(" #n ")" ::: "memory");   \
    __builtin_amdgcn_sched_barrier(0);                      \
  } while (0)

// acc (scalar) += dot(xv, wv)
#define DOT_ACC(a, xv, wv) \
  a = fmaf((xv).w, (wv).w, fmaf((xv).z, (wv).z, fmaf((xv).y, (wv).y, fmaf((xv).x, (wv).x, (a)))))
// acc (float4 over b) += s * v (float4 over b)
#define AXPY4(acc, s, v) do { \
  (acc).x = fmaf((s), (v).x, (acc).x); \
  (acc).y = fmaf((s), (v).y, (acc).y); \
  (acc).z = fmaf((s), (v).z, (acc).z); \
  (acc).w = fmaf((s), (v).w, (acc).w); } while (0)

__global__ __launch_bounds__(TPB, 2) void lstm_pipe(
    const int* __restrict__ src, const int* __restrict__ sen_len,
    const float* __restrict__ emb,
    const float* __restrict__ Wih0, const float* __restrict__ Whh0,
    const float* __restrict__ bih0, const float* __restrict__ bhh0,
    const float* __restrict__ Wih1, const float* __restrict__ Whh1,
    const float* __restrict__ bih1, const float* __restrict__ bhh1,
    float* __restrict__ out,
    int* __restrict__ barp, float* __restrict__ h0ring, float* __restrict__ h1ring)
{
  extern __shared__ char smem_raw[];
  float4* WlV  = (float4*)smem_raw;            // 4096 float4 = 64 KB: [kc][16 rows]
  float*  part = (float*)(smem_raw + 65536);   // 8192 floats = 32 KB: [kh][row][b]
  GBar* bar = (GBar*)barp;

  const int wg    = blockIdx.x;
  const int layer = wg >> 7;    // 0: WGs 0..127 (layer0 @ t=s), 1: WGs 128..255 (layer1 @ t=s-1)
  const int w     = wg & 127;   // owns hidden units j in [4w, 4w+4)
  const int tid   = threadIdx.x;
  const int kh    = tid >> 6;   // 0..7  K-segment of 128
  const int lane  = tid & 63;
  const int bg    = lane >> 2;  // 0..15 batch-group (4 batches)
  const int rg    = lane & 3;   // 0..3  j within WG
  const int b0    = bg << 2;    // batches b0..b0+3 (contiguous)
  const int k0    = kh << 7;    // K range [k0, k0+128)

  const float* Wih = layer ? Wih1 : Wih0;
  const float* Whh = layer ? Whh1 : Whh0;

  // Stage 16 rows x 1024 K of fused [Wih | Whh] weights into LDS, [kc][16] float4.
  for (int idx = tid; idx < 4096; idx += TPB) {
    int rowl = idx & 15;          // q*4 + rjj
    int kc   = idx >> 4;          // 0..255
    int q = rowl >> 2, rjj = rowl & 3;
    int grow = q * HID + (w << 2) + rjj;   // global gate row
    int k4 = kc << 2;
    float4 v;
    if (k4 < EMB) v = *(const float4*)(Wih + (size_t)grow * EMB + k4);
    else          v = *(const float4*)(Whh + (size_t)grow * HID + (k4 - EMB));
    WlV[kc * 16 + rowl] = v;
  }

  // Activation-phase identity: threads 0..255 own cell (jj, b); c lives here.
  const int p_b  = tid & 63;
  const int p_jj = (tid >> 6) & 3;
  const int p_jg = (w << 2) + p_jj;
  float bias4[4] = {0.f, 0.f, 0.f, 0.f};
  float c = 0.f;
  int   slen = -2;
  if (tid < 256) {
#pragma unroll
    for (int q = 0; q < 4; ++q) {
      int r = q * HID + p_jg;
      bias4[q] = layer ? (bih1[r] + bhh1[r]) : (bih0[r] + bhh0[r]);
    }
    slen = sen_len[p_b];
  }
  __syncthreads();

  for (int s = 0; s <= T_LEN; ++s) {
    const bool active = (layer == 0) ? (s < T_LEN) : (s >= 1);
    if (active) {
      const int t = (layer == 0) ? s : (s - 1);
      float4 acc[4];
#pragma unroll
      for (int q = 0; q < 4; ++q) acc[q] = make_float4(0.f, 0.f, 0.f, 0.f);

      if (layer == 0 && kh < 4) {
        // ---- embedding-gather mode: read-only data, normal cached loads ----
        const int* st = src + t * BATCH + b0;
        const float* e0 = emb + (size_t)st[0] * EMB;
        const float* e1 = emb + (size_t)st[1] * EMB;
        const float* e2 = emb + (size_t)st[2] * EMB;
        const float* e3 = emb + (size_t)st[3] * EMB;
#pragma unroll 4
        for (int kk = 0; kk < 128; kk += 4) {
          const int k  = k0 + kk;
          const int kc = k >> 2;
          float4 x0 = *(const float4*)(e0 + k);
          float4 x1 = *(const float4*)(e1 + k);
          float4 x2 = *(const float4*)(e2 + k);
          float4 x3 = *(const float4*)(e3 + k);
#pragma unroll
          for (int q = 0; q < 4; ++q) {
            float4 wq = WlV[kc * 16 + (q << 2) + rg];
            DOT_ACC(acc[q].x, x0, wq);
            DOT_ACC(acc[q].y, x1, wq);
            DOT_ACC(acc[q].z, x2, wq);
            DOT_ACC(acc[q].w, x3, wq);
          }
        }
      } else {
        // ---- transposed-ring mode: coherent dwordx4 loads, SW-pipelined ----
        const float* xT;
        if (layer == 0) {
          xT = h0ring + ((s + 1) & 1) * RING_SLOT + (k0 - EMB) * BATCH;
        } else if (kh < 4) {
          xT = h0ring + ((s - 1) & 1) * RING_SLOT + k0 * BATCH;
        } else {
          xT = h1ring + ((s - 1) & 1) * RING_SLOT + (k0 - EMB) * BATCH;
        }
        const float* p = xT + b0;   // thread's panel: float4 at p + kk*BATCH, kk in [0,128)

        float4 xa[16], xb[16];
        Issue16<0, 16>::go(xa, p);                 // group 0 in flight
#pragma unroll
        for (int g = 0; g < 8; ++g) {
          float4* cur = (g & 1) ? xb : xa;
          float4* nxt = (g & 1) ? xa : xb;
          if (g < 7) {
            Issue16<0, 16>::go(nxt, p + (g + 1) * 16 * BATCH);  // next group in flight
            WAIT_VM(16);   // oldest 16 (cur) complete; newest 16 still flying
          } else {
            WAIT_VM(0);
          }
#pragma unroll
          for (int ib = 0; ib < 4; ++ib) {
            const int kc = (k0 + (g << 4) + (ib << 2)) >> 2;
#pragma unroll
            for (int q = 0; q < 4; ++q) {
              float4 wq = WlV[kc * 16 + (q << 2) + rg];
              AXPY4(acc[q], wq.x, cur[(ib << 2) + 0]);
              AXPY4(acc[q], wq.y, cur[(ib << 2) + 1]);
              AXPY4(acc[q], wq.z, cur[(ib << 2) + 2]);
              AXPY4(acc[q], wq.w, cur[(ib << 2) + 3]);
            }
          }
        }
      }
      // write partials: part[kh][row][b], row = q*4+rg, b = b0..b0+3
#pragma unroll
      for (int q = 0; q < 4; ++q)
        *(float4*)(part + (kh << 10) + (((q << 2) + rg) << 6) + b0) = acc[q];
    }

    __syncthreads();  // partials visible

    if (active && tid < 256) {
      float g4[4];
#pragma unroll
      for (int q = 0; q < 4; ++q) {
        float a = bias4[q];
        const int base = (((q << 2) + p_jj) << 6) + p_b;
#pragma unroll
        for (int kk = 0; kk < 8; ++kk) a += part[(kk << 10) + base];
        g4[q] = a;
      }
      float ig = sigm(g4[0]), fg = sigm(g4[1]), gg = tanh_fast(g4[2]), og = sigm(g4[3]);
      c = fmaf(fg, c, ig * gg);
      float h = og * tanh_fast(c);
      float* ring = (layer == 0 ? h0ring : h1ring) + (s & 1) * RING_SLOT;
      cstore(ring + p_jg * BATCH + p_b, h);   // coherent store [j][b], coalesced
      if (layer == 1) {
        const int t = s - 1;
        if (t == slen - 1) out[p_b * HID + p_jg] = h;
      }
    }

    // ---- hierarchical grid barrier, all-RELAXED, monotonic counters ----
    // __syncthreads() drains vmcnt(0): every coherent h-store is committed at
    // the IF coherence point before tid0's arrival increment. Consumers read
    // ring data with coherent (sc0 sc1) loads after observing the release —
    // no cache maintenance (buffer_inv / buffer_wbl2) anywhere.
    __syncthreads();
    if (tid == 0) {
      const int target = s + 1;
      int* leafp = &bar->leaf[(wg >> 4) * 32];
      int* gepp  = &bar->gep[(wg >> 4) * 32];
      int prev = __hip_atomic_fetch_add(leafp, 1, __ATOMIC_RELAXED, __HIP_MEMORY_SCOPE_AGENT);
      if ((prev & 15) == 15) {   // 16th arrival of this slot in this group
        int r = __hip_atomic_fetch_add(&bar->root, 1, __ATOMIC_RELAXED, __HIP_MEMORY_SCOPE_AGENT);
        if ((r & 15) == 15) {    // 16th group — release everyone
          __hip_atomic_store(&bar->epoch, target, __ATOMIC_RELAXED, __HIP_MEMORY_SCOPE_AGENT);
        } else {
          while (__hip_atomic_load(&bar->epoch, __ATOMIC_RELAXED, __HIP_MEMORY_SCOPE_AGENT) < target)
            __builtin_amdgcn_s_sleep(1);
        }
        __hip_atomic_store(gepp, target, __ATOMIC_RELAXED, __HIP_MEMORY_SCOPE_AGENT);
      } else {
        while (__hip_atomic_load(gepp, __ATOMIC_RELAXED, __HIP_MEMORY_SCOPE_AGENT) < target)
          __builtin_amdgcn_s_sleep(1);
      }
    }
    __syncthreads();
  }
}

extern "C" void kernel_launch(void* const* d_in, const int* in_sizes, int n_in,
                              void* d_out, int out_size, void* d_ws, size_t ws_size,
                              hipStream_t stream) {
  const int*   src  = (const int*)d_in[0];
  const int*   slen = (const int*)d_in[1];
  const float* emb  = (const float*)d_in[2];
  const float* Wih0 = (const float*)d_in[3];
  const float* Whh0 = (const float*)d_in[4];
  const float* bih0 = (const float*)d_in[5];
  const float* bhh0 = (const float*)d_in[6];
  const float* Wih1 = (const float*)d_in[7];
  const float* Whh1 = (const float*)d_in[8];
  const float* bih1 = (const float*)d_in[9];
  const float* bhh1 = (const float*)d_in[10];
  float* out = (float*)d_out;

  int*   bar    = (int*)d_ws;
  float* h0ring = (float*)((char*)d_ws + 8192);
  float* h1ring = h0ring + 2 * RING_SLOT;

  // zero barrier state + all 4 ring slots (ws is poisoned 0xAA before every launch)
  int zero_ints = (8192 + 4 * RING_SLOT * 4) / 4;
  hipLaunchKernelGGL(init_ws_kernel, dim3(64), dim3(256), 0, stream, (int*)d_ws, zero_ints);

  (void)hipFuncSetAttribute((const void*)lstm_pipe,
                            hipFuncAttributeMaxDynamicSharedMemorySize, 98304);

  hipLaunchKernelGGL(lstm_pipe, dim3(NWG), dim3(TPB), 98304, stream,
                     src, slen, emb, Wih0, Whh0, bih0, bhh0, Wih1, Whh1, bih1, bhh1,
                     out, bar, h0ring, h1ring);
}